// Round 5
// baseline (149.807 us; speedup 1.0000x reference)
//
#include <hip/hip_runtime.h>
#include <hip/hip_bf16.h>

#define NN 65536
#define KK 2048
#define DD 128

typedef __attribute__((ext_vector_type(8))) _Float16 f16x8;
typedef __attribute__((ext_vector_type(4))) float f32x4;

static __device__ __forceinline__ unsigned encf(float f) {
    unsigned u = __float_as_uint(f);
    return u ^ (((unsigned)((int)u >> 31)) | 0x80000000u);   // monotone float->uint
}

static __device__ __forceinline__ void gll16(const void* g, void* l) {
    __builtin_amdgcn_global_load_lds(
        (const __attribute__((address_space(1))) void*)g,
        (__attribute__((address_space(3))) void*)l, 16, 0, 0);
}

// ---- fused prep ----
// Zre: [rowblk64][t:4][g:4][row64][8]   (f16, x1)
// Wre: [colblk64][t:5][g:4][col64][8]   (f16, x128; t=4 is the w2 fold-in:
//        only (g==0,j==0) nonzero = 8*w2, pairing with A-side const -8
//        so acc = 128*z.w - 64*w2 = -64*(w2 - 2 z.w))
__global__ __launch_bounds__(256) void vq_prep(const float* __restrict__ Z,
                                               const float* __restrict__ Wd,
                                               _Float16* __restrict__ Zre,
                                               _Float16* __restrict__ Wre,
                                               float* __restrict__ w2)
{
    int tid = threadIdx.x;
    int rl = tid >> 4, c = tid & 15;          // 16 rows x 16 chunks of 8
    int row = blockIdx.x * 16 + rl;
    bool isW = row >= NN;
    int r = isW ? row - NN : row;
    const float* src = isW ? Wd : Z;

    const float4* zp = reinterpret_cast<const float4*>(src + (size_t)r * DD + c * 8);
    float4 v0 = zp[0], v1 = zp[1];
    float v[8] = {v0.x, v0.y, v0.z, v0.w, v1.x, v1.y, v1.z, v1.w};

    float scale = isW ? 128.0f : 1.0f;
    f16x8 hv;
#pragma unroll
    for (int j = 0; j < 8; ++j) hv[j] = (_Float16)(v[j] * scale);

    int ts = c >> 2, g = c & 3;
    if (!isW) {
        size_t off = ((size_t)(r >> 6) * 16 + ts * 4 + g) * 512 + (size_t)(r & 63) * 8;
        *reinterpret_cast<f16x8*>(Zre + off) = hv;
    } else {
        size_t base = (size_t)(r >> 6) * 10240;
        *reinterpret_cast<f16x8*>(Wre + base + (ts * 4 + g) * 512 + (size_t)(r & 63) * 8) = hv;
        // w2 via 16-lane reduce
        float p = 0.f;
#pragma unroll
        for (int j = 0; j < 8; ++j) p = fmaf(v[j], v[j], p);
#pragma unroll
        for (int off2 = 1; off2 < 16; off2 <<= 1) p += __shfl_xor(p, off2, 64);
        if (c == 0) {
            w2[r] = p;
            f16x8 zf = {};
            f16x8 b4 = zf;
            b4[0] = (_Float16)(8.0f * p);
#pragma unroll
            for (int gg = 0; gg < 4; ++gg)
                *reinterpret_cast<f16x8*>(Wre + base + (16 + gg) * 512 + (size_t)(r & 63) * 8)
                    = (gg == 0) ? b4 : zf;
        }
    }
}

// ---- MFMA distance GEMM, counted-vmcnt pipelined ----
// block = 64 rows x 2048 cols; per cb: 64-col, K=160 tile (20KB) staged.
__global__ __launch_bounds__(256, 4) void vq_gemm(const _Float16* __restrict__ Zre,
                                                  const _Float16* __restrict__ Wre,
                                                  float* __restrict__ top2)
{
    int rb  = blockIdx.x;
    int tid = threadIdx.x;
    int wid = tid >> 6, lane = tid & 63;
    int wr = wid >> 1, wc = wid & 1;          // wave tile 32r x 32c
    int g = lane >> 4, l15 = lane & 15;

    __shared__ _Float16 Bs[2][10240];         // 2 x 20KB

    // A fragments: 32 rows x 128 k -> 8 x f16x8 = 32 VGPR
    const _Float16* zb = Zre + (size_t)rb * 8192;
    f16x8 a[4][2];
#pragma unroll
    for (int t = 0; t < 4; ++t)
#pragma unroll
        for (int m = 0; m < 2; ++m)
            a[t][m] = *reinterpret_cast<const f16x8*>(
                zb + ((t * 4 + g) * 512 + (wr * 32 + m * 16 + l15) * 8));
    // augmented-K A frag: -8 at k=128 (g==0, j==0)
    f16x8 a4 = {};
    if (g == 0) a4[0] = (_Float16)(-8.0f);

    const float NINF = __uint_as_float(0xFF800000u);
    float b1[8], b2[8];
#pragma unroll
    for (int s = 0; s < 8; ++s) { b1[s] = NINF; b2[s] = NINF; }

    const f32x4 zz = {0.f, 0.f, 0.f, 0.f};

    // prologue: stage cb=0 into buf 0, drain, barrier
#pragma unroll
    for (int j = 0; j < 5; ++j)
        gll16(Wre + j * 2048 + tid * 8, &Bs[0][j * 2048 + tid * 8]);
    asm volatile("s_waitcnt vmcnt(0)" ::: "memory");
    __builtin_amdgcn_s_barrier();
    __builtin_amdgcn_sched_barrier(0);

    int cur = 0;
    for (int cb = 0; cb < 32; ++cb) {
        if (cb < 31) {
            const _Float16* wb = Wre + (size_t)(cb + 1) * 10240;
#pragma unroll
            for (int j = 0; j < 5; ++j)
                gll16(wb + j * 2048 + tid * 8, &Bs[cur ^ 1][j * 2048 + tid * 8]);
            asm volatile("s_waitcnt vmcnt(5)" ::: "memory");   // cur's 5 done, next's 5 fly
        } else {
            asm volatile("s_waitcnt vmcnt(0)" ::: "memory");
        }
        __builtin_amdgcn_s_barrier();
        __builtin_amdgcn_sched_barrier(0);

        const _Float16* bb = Bs[cur];
        f32x4 acc[2][2];
#pragma unroll
        for (int t = 0; t < 4; ++t) {
            f16x8 b[2];
#pragma unroll
            for (int n = 0; n < 2; ++n)
                b[n] = *reinterpret_cast<const f16x8*>(
                    bb + ((t * 4 + g) * 512 + (wc * 32 + n * 16 + l15) * 8));
#pragma unroll
            for (int m = 0; m < 2; ++m)
#pragma unroll
                for (int n = 0; n < 2; ++n)
                    acc[m][n] = __builtin_amdgcn_mfma_f32_16x16x32_f16(
                        a[t][m], b[n], (t == 0) ? zz : acc[m][n], 0, 0, 0);
        }
        {   // augmented k-tile: folds in -64*w2
            f16x8 b[2];
#pragma unroll
            for (int n = 0; n < 2; ++n)
                b[n] = *reinterpret_cast<const f16x8*>(
                    bb + ((16 + g) * 512 + (wc * 32 + n * 16 + l15) * 8));
#pragma unroll
            for (int m = 0; m < 2; ++m)
#pragma unroll
                for (int n = 0; n < 2; ++n)
                    acc[m][n] = __builtin_amdgcn_mfma_f32_16x16x32_f16(a4, b[n], acc[m][n], 0, 0, 0);
        }

        // epilogue: acc = -64*d ; track top-2 MAX, index in low 11 bits. 3 VALU/value
        int cg0 = cb * 64 + wc * 32 + l15;
#pragma unroll
        for (int m = 0; m < 2; ++m)
#pragma unroll
            for (int n = 0; n < 2; ++n)
#pragma unroll
                for (int r = 0; r < 4; ++r) {
                    unsigned ub = (__float_as_uint(acc[m][n][r]) & 0xFFFFF800u)
                                  | (unsigned)(cg0 + n * 16);
                    float df = __uint_as_float(ub);
                    int s = m * 4 + r;
                    b2[s] = __builtin_amdgcn_fmed3f(df, b2[s], b1[s]);
                    b1[s] = fmaxf(b1[s], df);
                }

        __builtin_amdgcn_s_barrier();
        cur ^= 1;
    }

    // cross-lane merge (max semantics) within 16-lane col groups
#pragma unroll
    for (int s = 0; s < 8; ++s) {
        float v1 = b1[s], v2 = b2[s];
#pragma unroll
        for (int msk = 1; msk < 16; msk <<= 1) {
            float o1 = __shfl_xor(v1, msk, 64);
            float o2 = __shfl_xor(v2, msk, 64);
            float lo = fminf(v1, o1);
            v1 = fmaxf(v1, o1);
            v2 = fmaxf(lo, fmaxf(v2, o2));
        }
        if (l15 == 0) {
            int row = rb * 64 + wr * 32 + (s >> 2) * 16 + g * 4 + (s & 3);
            top2[(size_t)row * 4 + wc * 2 + 0] = v1;
            top2[(size_t)row * 4 + wc * 2 + 1] = v2;
        }
    }
}

// ---- resolve: best of 4 candidates; exact fp32 re-score if within delta ----
__global__ __launch_bounds__(256) void vq_resolve(const float* __restrict__ top2,
                                                  const float* __restrict__ Z,
                                                  const float* __restrict__ Wd,
                                                  const float* __restrict__ w2,
                                                  int* __restrict__ assign)
{
    int row = blockIdx.x * 256 + threadIdx.x;
    float4 t4 = *reinterpret_cast<const float4*>(top2 + (size_t)row * 4);
    float vv[4] = {t4.x, t4.y, t4.z, t4.w};
    float dv[4];
    int dc[4];
#pragma unroll
    for (int i = 0; i < 4; ++i) {
        unsigned b = __float_as_uint(vv[i]);
        dc[i] = (int)(b & 2047u);
        dv[i] = __uint_as_float(b & 0xFFFFF800u) * (-0.015625f);   // d = facc * (-1/64)
    }
    int ib = 0;
#pragma unroll
    for (int i = 1; i < 4; ++i)
        if (dv[i] < dv[ib]) ib = i;
    float lim = dv[ib] + 1e-3f;
    int cols[4];
    int nc = 0;
#pragma unroll
    for (int i = 0; i < 4; ++i)
        if (dv[i] <= lim) cols[nc++] = dc[i];

    int res = dc[ib];
    if (nc > 1) {
        const float4* zp = reinterpret_cast<const float4*>(Z + (size_t)row * DD);
        float s0 = 0.f, s1 = 0.f, s2 = 0.f, s3 = 0.f;
        for (int q = 0; q < 32; ++q) {
            float4 z = zp[q];
            s0 = fmaf(z.x, z.x, s0);
            s1 = fmaf(z.y, z.y, s1);
            s2 = fmaf(z.z, z.z, s2);
            s3 = fmaf(z.w, z.w, s3);
        }
        float z2v = (s0 + s1) + (s2 + s3);
        unsigned long long be = ~0ull;
        for (int i = 0; i < nc; ++i) {
            int k = cols[i];
            const float4* wp = reinterpret_cast<const float4*>(Wd + (size_t)k * DD);
            float a0 = 0.f, a1 = 0.f, a2 = 0.f, a3 = 0.f;
            for (int q = 0; q < 32; ++q) {
                float4 zq = zp[q];
                float4 wq = wp[q];
                a0 = fmaf(zq.x, wq.x, a0);
                a1 = fmaf(zq.y, wq.y, a1);
                a2 = fmaf(zq.z, wq.z, a2);
                a3 = fmaf(zq.w, wq.w, a3);
            }
            float sdot = (a0 + a1) + (a2 + a3);
            float t = __fsub_rn(z2v, __fmul_rn(2.0f, sdot));
            float dist = __fadd_rn(t, w2[k]);
            unsigned long long key = (((unsigned long long)encf(dist)) << 32) | (unsigned)k;
            if (key < be) be = key;
        }
        res = (int)(be & 0xffffffffu);
    }
    assign[row] = res;
}

// ---- scatter: 1 element-atomic per thread, coalesced ----
__global__ __launch_bounds__(256) void vq_scatter(const float* __restrict__ Z,
                                                  const int* __restrict__ assign,
                                                  float* __restrict__ counts,
                                                  float* __restrict__ sums)
{
    int t = blockIdx.x * 256 + threadIdx.x;   // 0 .. N*D-1
    int row = t >> 7, d = t & 127;
    int k = assign[row];
    atomicAdd(&sums[(size_t)k * DD + d], Z[t]);
    if (d == 0) atomicAdd(&counts[k], 1.0f);
}

// ---- update: c_new, w_new ----
__global__ __launch_bounds__(256) void vq_update(const float* __restrict__ Wd,
                                                 const float* __restrict__ dict_cnt,
                                                 const float* __restrict__ counts,
                                                 const float* __restrict__ sums,
                                                 float* __restrict__ w_new_out,
                                                 float* __restrict__ c_new_out)
{
    int t = blockIdx.x * 256 + threadIdx.x;
    int k = t >> 7, d = t & 127;
    float cnt = dict_cnt[k];
    float ck = counts[k];
    bool assigned = ck > 0.f;
    float cn = assigned ? __fadd_rn(__fmul_rn(0.99f, cnt), __fmul_rn(0.01f, ck)) : cnt;
    float w = Wd[t];
    float wn = w;
    if (assigned) {
        float num = __fmul_rn(0.01f, sums[t]);
        wn = __fadd_rn(__fmul_rn(0.99f, w), num / fmaxf(cn, 1e-12f));
    }
    w_new_out[t] = wn;
    if (d == 0) c_new_out[k] = cn;
}

// ---- gather: st_out = w_new[i]; commit-loss partials ----
__global__ __launch_bounds__(256) void vq_gather(const float* __restrict__ Z,
                                                 const int* __restrict__ assign,
                                                 const float* __restrict__ w_new,
                                                 float* __restrict__ st_out,
                                                 float* __restrict__ loss_bins)
{
    int wave = threadIdx.x >> 6;
    int lane = threadIdx.x & 63;
    int row = blockIdx.x * 4 + wave;
    int k = assign[row];

    const float2* zp = reinterpret_cast<const float2*>(Z + (size_t)row * DD);
    const float2* wp = reinterpret_cast<const float2*>(w_new + (size_t)k * DD);
    float2 z = zp[lane];
    float2 w = wp[lane];
    reinterpret_cast<float2*>(st_out + (size_t)row * DD)[lane] = w;

    float dx = z.x - w.x, dy = z.y - w.y;
    float part = fmaf(dx, dx, dy * dy);
#pragma unroll
    for (int off = 32; off; off >>= 1) part += __shfl_down(part, off, 64);

    __shared__ float sm[4];
    if (lane == 0) sm[wave] = part;
    __syncthreads();
    if (threadIdx.x == 0) {
        float s = (sm[0] + sm[1]) + (sm[2] + sm[3]);
        atomicAdd(&loss_bins[(blockIdx.x & 255) * 16], s);
    }
}

__global__ void vq_finish(const float* __restrict__ loss_bins,
                          float* __restrict__ out_loss)
{
    if (threadIdx.x == 0) {
        float s = 0.f;
        for (int i = 0; i < 256; ++i) s += loss_bins[i * 16];
        out_loss[0] = s * (1.0f / 65536.0f);
    }
}

extern "C" void kernel_launch(void* const* d_in, const int* in_sizes, int n_in,
                              void* d_out, int out_size, void* d_ws, size_t ws_size,
                              hipStream_t stream)
{
    const float* Z        = (const float*)d_in[0];
    const float* Wd       = (const float*)d_in[1];
    const float* dict_cnt = (const float*)d_in[2];

    float* out      = (float*)d_out;
    float* st_out   = out;
    float* out_loss = out + (size_t)NN * DD;
    float* w_new    = out_loss + 1;
    float* c_new    = w_new + (size_t)KK * DD;

    char* ws = (char*)d_ws;
    _Float16* Zre = (_Float16*)ws;                       // 16,777,216 B
    _Float16* Wre = (_Float16*)(ws + 16777216);          //    655,360 B (K=160 aug)
    float* w2     = (float*)(ws + 17432576);             //      8,192 B
    float* top2   = (float*)(ws + 17440768);             //  1,048,576 B
    int* assign   = (int*)(ws + 18489344);               //    262,144 B
    float* counts = (float*)(ws + 18751488);             //      8,192 B
    float* sums   = (float*)(ws + 18759680);             //  1,048,576 B
    float* bins   = (float*)(ws + 19808256);             //     16,384 B

    // counts + sums + bins contiguous: one memset
    hipMemsetAsync(counts, 0, 8192 + 1048576 + 16384, stream);

    vq_prep<<<(NN + KK) / 16, 256, 0, stream>>>(Z, Wd, Zre, Wre, w2);
    vq_gemm<<<NN / 64, 256, 0, stream>>>(Zre, Wre, top2);
    vq_resolve<<<NN / 256, 256, 0, stream>>>(top2, Z, Wd, w2, assign);
    vq_scatter<<<(NN * DD) / 256, 256, 0, stream>>>(Z, assign, counts, sums);
    vq_update<<<(KK * DD) / 256, 256, 0, stream>>>(Wd, dict_cnt, counts, sums, w_new, c_new);
    vq_gather<<<NN / 4, 256, 0, stream>>>(Z, assign, w_new, st_out, bins);
    vq_finish<<<1, 64, 0, stream>>>(bins, out_loss);
}